// Round 5
// baseline (573.921 us; speedup 1.0000x reference)
//
#include <hip/hip_runtime.h>
#include <cstdint>
#include <cstddef>

// ---- problem constants ----
// DIM=512, HEADS=8, B=8, H=64, W=64, SPLIT=8 -> windows are full-height
// vertical stripes: 64 windows (b*8+wx), S=512 tokens (s=y*8+xl), head_dim=64.
// Inputs are float32; OUTPUT is float32 (reference returns jnp.float32).
// Internal matmuls use bf16 MFMA (error ~1e-4 << 9.1e-3 threshold).
//
// v5 (resubmit — round 4 was an infra failure, kernel never ran):
// single fused kernel, conv moved to a POST-phase-2 tail.
// Round-3 (conv-first, lepe as MFMA C-init) failed at absmax 0.14 even
// though the conv content matches the round-1 passing lepe kernel term
// by term; the suspect is the early placement (oacc live across phase 1
// + triple LDS aliasing under later stages). v5 keeps phases 1-2 BIT-
// IDENTICAL to the round-1 passing attn kernel (oacc zero-init), then:
// sync -> stage weights+halo into dead K/V/Q LDS -> sync -> conv inside
// the epilogue using the SAME srow/oi expressions -> pure store.

typedef float f32x4 __attribute__((ext_vector_type(4)));
typedef __bf16 bf16x8 __attribute__((ext_vector_type(8)));

__device__ __forceinline__ unsigned short f2bf(float f) {
  union { float f; unsigned int u; } t; t.f = f;
  unsigned int u = t.u;
  return (unsigned short)((u + 0x7fffu + ((u >> 16) & 1u)) >> 16);
}

// =====================================================================
// Fused windowed attention (polar RPE + L1-normalized cosine activation)
// + lepe depthwise 3x3 conv tail, pure-store epilogue.
// Grid: 4096 = 64 windows * 8 heads * 8 row-tiles; block 256 (4 waves),
// each wave owns 16 Q-rows; full 16x512 score tile in MFMA accumulators.
// T1 bijective XCD swizzle (measured: FETCH 610->445MB, dur 293->264us).
// =====================================================================
__global__ __launch_bounds__(256, 2)
void attn_kernel(const float* __restrict__ temp,
                 const float* __restrict__ polar,
                 const float* __restrict__ cw,
                 const float* __restrict__ cbias,
                 float* __restrict__ out)
{
  // carved LDS block; conv tail aliases regions that are dead by then:
  //   [0,18432)      sm_kv   K:[128][72] / V:[64][136] bf16
  //   [18432,27648)  sm_q    Q tile [tok][d+8] bf16
  //   [27648,32768)  sm_attn per-wave attn A-frag [16][40] bf16
  //   [32768,34816)  sm_phi  [512] f32
  //   conv tail:  sm_vh = [0,25856) f32 [64ch][100, stride 101]
  //               sm_wb = [27648,30208) f32 [64ch][10] (9 wgt + bias)
  __shared__ __align__(16) unsigned char smem[34816];
  unsigned short* sm_kv   = (unsigned short*)smem;
  unsigned short* sm_q    = (unsigned short*)(smem + 18432);
  unsigned short* sm_attn = (unsigned short*)(smem + 27648);
  float* sm_phi           = (float*)(smem + 32768);
  float* sm_vh            = (float*)smem;            // tail alias (kv+q dead)
  float* sm_wb            = (float*)(smem + 27648);  // tail alias (attn dead)

  const int t    = threadIdx.x;
  const int lane = t & 63;
  const int wv   = t >> 6;      // wave 0..3
  const int l15  = lane & 15;
  const int q4   = lane >> 4;   // quad 0..3

  // XCD-aware swizzle: hw round-robins blockIdx%8 across XCDs; remap so
  // logical ids 0..511 (all rt+heads of windows 0..7) share XCD 0, etc.
  const int bid0 = blockIdx.x;
  const int bid  = ((bid0 & 7) << 9) | (bid0 >> 3);
  const int wi  = bid >> 6;         // window 0..63 (rt fastest -> K/V L2 reuse)
  const int hh  = (bid >> 3) & 7;   // head
  const int rt  = bid & 7;          // row-tile (64 rows)
  const int b   = wi >> 3;
  const int wx  = wi & 7;

  const size_t img = (size_t)512 * 4096;                 // elems per [B,C,H,W] tensor
  const size_t base_bh = (size_t)b * img + (size_t)(hh * 64) * 4096 + wx * 8;
  const float* qp = temp + base_bh;             // temp[0]
  const float* kp = temp + 8 * img + base_bh;   // temp[1]
  const float* vp = temp + 16 * img + base_bh;  // temp[2]
  // channel-plane base for the conv halo (no wx column offset)
  const float* vch = temp + 16 * img + (size_t)b * img + (size_t)(hh * 64) * 4096;

  // ---- stage phi for the whole window (coord[...,1]) ----
  for (int i = t; i < 512; i += 256) {
    const int y = i >> 3, xl = i & 7;
    sm_phi[i] = polar[((size_t)b * 4096 + y * 64 + wx * 8 + xl) * 2 + 1];
  }

  // ---- stage Q tile (64 tokens x 64 d): fp32 -> bf16, transpose to [tok][d] ----
  #pragma unroll
  for (int it = 0; it < 4; ++it) {
    const int idx = it * 256 + t;       // 0..1023
    const int h   = idx & 1;
    const int dch = (idx >> 1) & 63;
    const int y8  = idx >> 7;           // 0..7
    const float4 v4 = *(const float4*)(qp + (size_t)dch * 4096 + (rt * 8 + y8) * 64 + h * 4);
    const int tok = y8 * 8 + h * 4;
    sm_q[(tok + 0) * 72 + dch] = f2bf(v4.x);
    sm_q[(tok + 1) * 72 + dch] = f2bf(v4.y);
    sm_q[(tok + 2) * 72 + dch] = f2bf(v4.z);
    sm_q[(tok + 3) * 72 + dch] = f2bf(v4.w);
  }
  __syncthreads();

  // Q A-fragments (resident): A[m=l15][k=q4*8+j], k-chunks of 32 over d=64
  bf16x8 qf[2];
  #pragma unroll
  for (int kc = 0; kc < 2; ++kc)
    qf[kc] = __builtin_bit_cast(
        bf16x8, *(const uint4*)&sm_q[(wv * 16 + l15) * 72 + kc * 32 + q4 * 8]);

  // ---- phase 1: score = Q K^T, K staged in 4 chunks of 128 tokens ----
  f32x4 acc[32];
  #pragma unroll
  for (int jt = 0; jt < 32; ++jt) acc[jt] = (f32x4){0.f, 0.f, 0.f, 0.f};

  unsigned short* smk = sm_kv;
  #pragma unroll
  for (int ch = 0; ch < 4; ++ch) {
    __syncthreads();
    #pragma unroll
    for (int it = 0; it < 8; ++it) {
      const int idx = it * 256 + t;     // 0..2047
      const int h   = idx & 1;
      const int dch = (idx >> 1) & 63;
      const int yl  = idx >> 7;         // 0..15
      const float4 v4 = *(const float4*)(kp + (size_t)dch * 4096 + (ch * 16 + yl) * 64 + h * 4);
      const int tok = yl * 8 + h * 4;
      smk[(tok + 0) * 72 + dch] = f2bf(v4.x);
      smk[(tok + 1) * 72 + dch] = f2bf(v4.y);
      smk[(tok + 2) * 72 + dch] = f2bf(v4.z);
      smk[(tok + 3) * 72 + dch] = f2bf(v4.w);
    }
    __syncthreads();
    #pragma unroll
    for (int j8 = 0; j8 < 8; ++j8) {
      const int jt = ch * 8 + j8;
      const bf16x8 kf0 = __builtin_bit_cast(
          bf16x8, *(const uint4*)&smk[(j8 * 16 + l15) * 72 + q4 * 8]);
      const bf16x8 kf1 = __builtin_bit_cast(
          bf16x8, *(const uint4*)&smk[(j8 * 16 + l15) * 72 + 32 + q4 * 8]);
      acc[jt] = __builtin_amdgcn_mfma_f32_16x16x32_bf16(qf[0], kf0, acc[jt], 0, 0, 0);
      acc[jt] = __builtin_amdgcn_mfma_f32_16x16x32_bf16(qf[1], kf1, acc[jt], 0, 0, 0);
    }
  }

  // ---- scale + rpe + row L1 ----
  // C layout: lane holds score[row=q4*4+r][col=jt*16+l15]
  float phi_r[4];
  #pragma unroll
  for (int r = 0; r < 4; ++r)
    phi_r[r] = sm_phi[rt * 64 + wv * 16 + q4 * 4 + r];
  float l1p[4] = {0.f, 0.f, 0.f, 0.f};
  #pragma unroll
  for (int jt = 0; jt < 32; ++jt) {
    const float phi_c = sm_phi[jt * 16 + l15];
    #pragma unroll
    for (int r = 0; r < 4; ++r) {
      const float s = acc[jt][r] * 0.125f + (phi_r[r] - phi_c);
      acc[jt][r] = s;
      l1p[r] += fabsf(s);
    }
  }
  #pragma unroll
  for (int r = 0; r < 4; ++r) {
    float v = l1p[r];
    v += __shfl_xor(v, 1, 16);
    v += __shfl_xor(v, 2, 16);
    v += __shfl_xor(v, 4, 16);
    v += __shfl_xor(v, 8, 16);
    l1p[r] = 1.5707963267948966f / (v + 1e-8f);   // fold pi/2 into reciprocal
  }

  // ---- phase 2: out = attn @ V (attn = 2*sin^2(x/2) = 1-cos(x)) ----
  f32x4 oacc[4];
  #pragma unroll
  for (int nt = 0; nt < 4; ++nt) oacc[nt] = (f32x4){0.f, 0.f, 0.f, 0.f};

  unsigned short* smv = sm_kv;                  // reuse buffer as V [dch][136]
  unsigned short* sma = sm_attn + wv * (16 * 40);
  #pragma unroll
  for (int vc = 0; vc < 4; ++vc) {
    __syncthreads();
    #pragma unroll
    for (int it = 0; it < 8; ++it) {
      const int idx = it * 256 + t;
      const int h   = idx & 1;
      const int dch = (idx >> 1) & 63;
      const int yl  = idx >> 7;
      const float4 v4 = *(const float4*)(vp + (size_t)dch * 4096 + (vc * 16 + yl) * 64 + h * 4);
      uint2 p;
      p.x = (unsigned)f2bf(v4.x) | ((unsigned)f2bf(v4.y) << 16);
      p.y = (unsigned)f2bf(v4.z) | ((unsigned)f2bf(v4.w) << 16);
      *(uint2*)&smv[dch * 136 + yl * 8 + h * 4] = p;   // V wants [d][tok]
    }
    __syncthreads();
    #pragma unroll
    for (int k2 = 0; k2 < 4; ++k2) {            // 32 j-columns per iteration
      const int jt0 = vc * 8 + k2 * 2;
      #pragma unroll
      for (int jl = 0; jl < 2; ++jl) {
        const int jt = jt0 + jl;
        #pragma unroll
        for (int r = 0; r < 4; ++r) {
          const float x  = acc[jt][r] * l1p[r];
          const float sn = __sinf(0.5f * x);
          sma[(q4 * 4 + r) * 40 + jl * 16 + l15] = f2bf(2.f * sn * sn);
        }
      }
      // C-layout -> A-operand layout via per-wave LDS round-trip
      const bf16x8 af = __builtin_bit_cast(
          bf16x8, *(const uint4*)&sma[l15 * 40 + q4 * 8]);
      #pragma unroll
      for (int nt = 0; nt < 4; ++nt) {
        const bf16x8 vf = __builtin_bit_cast(
            bf16x8, *(const uint4*)&smv[(nt * 16 + l15) * 136 + k2 * 32 + q4 * 8]);
        oacc[nt] = __builtin_amdgcn_mfma_f32_16x16x32_bf16(af, vf, oacc[nt], 0, 0, 0);
      }
    }
  }

  // ---- conv tail: stage weights + 10x10 halo into dead LDS ----
  __syncthreads();     // all K/V/Q/attn LDS reads complete
  #pragma unroll
  for (int i2 = 0; i2 < 3; ++i2) {
    const int i = i2 * 256 + t;
    if (i < 640) {
      const int c = i / 10;
      const int j = i - c * 10;
      sm_wb[i] = (j < 9) ? cw[(hh * 64 + c) * 9 + j] : cbias[hh * 64 + c];
    }
  }
  // sm_vh[c*101 + ry*10 + cx] = v[hh*64+c][rt*8-1+ry][wx*8-1+cx], 0-padded
  #pragma unroll
  for (int it = 0; it < 25; ++it) {
    const int idx = it * 256 + t;            // 0..6399
    const int c   = idx / 100;
    const int pos = idx - c * 100;
    const int ry  = pos / 10;
    const int cx  = pos - ry * 10;
    const int yy = rt * 8 - 1 + ry;
    const int xx = wx * 8 - 1 + cx;
    float v = 0.f;
    if (yy >= 0 && yy < 64 && xx >= 0 && xx < 64)
      v = vch[(size_t)c * 4096 + yy * 64 + xx];
    sm_vh[c * 101 + pos] = v;
  }
  __syncthreads();

  // ---- epilogue: out = oacc + lepe (pure store). Halo indices derived
  //      from the SAME srow expression as the passing epilogue. ----
  #pragma unroll
  for (int nt = 0; nt < 4; ++nt) {
    const int cl = nt * 16 + l15;            // channel within head block
    float wg[9];
    #pragma unroll
    for (int j = 0; j < 9; ++j) wg[j] = sm_wb[cl * 10 + j];
    const float bs = sm_wb[cl * 10 + 9];
    #pragma unroll
    for (int r = 0; r < 4; ++r) {
      const int sl = wv * 16 + q4 * 4 + r;   // wave-local token = srow - rt*64
      const int hb = sl >> 3;                // halo row base = y - rt*8
      const int xl = sl & 7;                 // stripe col
      float a = bs;
      #pragma unroll
      for (int ky = 0; ky < 3; ++ky)
        #pragma unroll
        for (int kx = 0; kx < 3; ++kx)
          a += sm_vh[cl * 101 + (hb + ky) * 10 + xl + kx] * wg[ky * 3 + kx];
      const int srow = rt * 64 + sl;         // token in window
      const int y = srow >> 3, xg = srow & 7;
      const size_t oi = ((size_t)b * 4096 + y * 64 + wx * 8 + xg) * 512
                        + hh * 64 + nt * 16 + l15;
      out[oi] = oacc[nt][r] + a;
    }
  }
}

extern "C" void kernel_launch(void* const* d_in, const int* in_sizes, int n_in,
                              void* d_out, int out_size, void* d_ws, size_t ws_size,
                              hipStream_t stream) {
  const float* temp  = (const float*)d_in[0]; // [3,8,512,64,64] fp32
  const float* polar = (const float*)d_in[1]; // [8,64,64,2] fp32
  const float* cw    = (const float*)d_in[2]; // [512,1,3,3] fp32
  const float* cb    = (const float*)d_in[3]; // [512] fp32
  float* out = (float*)d_out;                 // [8,4096,512] fp32

  attn_kernel<<<4096, 256, 0, stream>>>(temp, polar, cw, cb, out);
}

// Round 6
// 492.745 us; speedup vs baseline: 1.1647x; 1.1647x over previous
//
#include <hip/hip_runtime.h>
#include <cstdint>
#include <cstddef>

// ---- problem constants ----
// DIM=512, HEADS=8, B=8, H=64, W=64, SPLIT=8 -> windows are full-height
// vertical stripes: 64 windows (b*8+wx), S=512 tokens (s=y*8+xl), head_dim=64.
// Inputs are float32; OUTPUT is float32. Internal matmuls bf16 MFMA.
//
// v6: REVERT to the two-kernel round-1 structure (best measured 515us;
// round-5 proved ~198us of the total is fixed harness overhead and the
// fused conv tail was +112us of un-overlapped HBM-missing halo reads).
// attn changes on top of round-1:
//  - T14 async-STAGE split on K and V chunk loops: next chunk's 8
//    float4 loads issue BEFORE the current chunk's MFMA phase; the
//    convert+LDS-write happens after the post-MFMA barrier. K0 hoisted
//    above Q staging; V0 latency hides under the rpe/L1 VALU pass.
//  - v_cvt_pk_bf16_f32 (inline asm, RNE = bit-identical to f2bf) for
//    the V pack.

typedef float f32x4 __attribute__((ext_vector_type(4)));
typedef __bf16 bf16x8 __attribute__((ext_vector_type(8)));

__device__ __forceinline__ unsigned short f2bf(float f) {
  union { float f; unsigned int u; } t; t.f = f;
  unsigned int u = t.u;
  return (unsigned short)((u + 0x7fffu + ((u >> 16) & 1u)) >> 16);
}

__device__ __forceinline__ unsigned cvtpk(float lo, float hi) {
  unsigned r;
  asm("v_cvt_pk_bf16_f32 %0, %1, %2" : "=v"(r) : "v"(lo), "v"(hi));
  return r;
}

// =====================================================================
// Kernel 1: lepe = depthwise 3x3 conv on v (fp32), written to d_out.
// (round-2 version, measured ~53us as part of the 515us total)
// =====================================================================
__global__ __launch_bounds__(256, 2)
void lepe_kernel(const float* __restrict__ temp,
                 const float* __restrict__ cw,
                 const float* __restrict__ cbias,
                 float* __restrict__ out)
{
  __shared__ float tile[64 * 256];   // 64KB, [c][p^(c&31)] XOR-swizzled
  const int t  = threadIdx.x;
  const int x  = t & 63;             // lane = image x (row width 64 = wave)
  const int w0 = t >> 6;             // wave 0..3
  const int bz = blockIdx.x;         // 1024 = 8b * 8cg * 16 ystrips
  const int b  = bz >> 7;
  const int cg = (bz >> 4) & 7;
  const int y0 = (bz & 15) * 4;
  const int cb = cg * 64;
  const float* vimg = temp + (size_t)16 * 2097152 + (size_t)b * 2097152; // temp[2][b]

  #pragma unroll 2
  for (int i = 0; i < 16; ++i) {
    const int cl = i * 4 + w0;                            // 0..63 wave-uniform
    const int c  = __builtin_amdgcn_readfirstlane(cb + cl);
    const float* wp = cw + c * 9;                         // uniform -> s_load
    float wgt[9];
    #pragma unroll
    for (int j = 0; j < 9; ++j) wgt[j] = wp[j];
    const float bias = cbias[c];
    const float* vc = vimg + (size_t)c * 4096;

    float m[6], l[6], r[6];
    #pragma unroll
    for (int j = 0; j < 6; ++j) {
      const int yy = y0 - 1 + j;
      float v = 0.f;
      if (yy >= 0 && yy <= 63) v = vc[yy * 64 + x];       // coalesced 256B
      m[j] = v;
      const float lu = __shfl_up(v, 1);                   // value at x-1
      const float rd = __shfl_down(v, 1);                 // value at x+1
      l[j] = (x == 0)  ? 0.f : lu;                        // SAME zero-pad
      r[j] = (x == 63) ? 0.f : rd;
    }
    #pragma unroll
    for (int oy = 0; oy < 4; ++oy) {
      float a = bias;
      #pragma unroll
      for (int ky = 0; ky < 3; ++ky) {
        const int j = oy + ky;                            // input row y0+oy-1+ky
        a += l[j] * wgt[ky * 3 + 0] + m[j] * wgt[ky * 3 + 1] + r[j] * wgt[ky * 3 + 2];
      }
      const int p = oy * 64 + x;
      tile[cl * 256 + (p ^ (cl & 31))] = a;               // conflict-free write
    }
  }
  __syncthreads();

  // write out: 256 positions x 64 channels; lanes cover 64 consecutive c
  const int c0 = (t & 15) * 4;
  const int ps = t >> 4;
  #pragma unroll 4
  for (int i = 0; i < 16; ++i) {
    const int p = ps + i * 16;       // 0..255
    const int y = p >> 6, xx = p & 63;
    float4 o;
    o.x = tile[(c0 + 0) * 256 + (p ^ ((c0 + 0) & 31))];
    o.y = tile[(c0 + 1) * 256 + (p ^ ((c0 + 1) & 31))];
    o.z = tile[(c0 + 2) * 256 + (p ^ ((c0 + 2) & 31))];
    o.w = tile[(c0 + 3) * 256 + (p ^ ((c0 + 3) & 31))];
    *(float4*)&out[((size_t)b * 4096 + (y0 + y) * 64 + xx) * 512 + cb + c0] = o;
  }
}

// =====================================================================
// Kernel 2: windowed attention with polar RPE + L1-normalized cosine
// activation; accumulates onto the lepe already in d_out (fp32 RMW).
// Grid: 4096 = 64 windows * 8 heads * 8 row-tiles; block 256 (4 waves),
// each wave owns 16 Q-rows; full 16x512 score tile in MFMA accumulators.
// T1 bijective XCD swizzle (measured: FETCH 610->445MB, dur 293->264us).
// v6: T14 prefetch (see header).
// =====================================================================
__global__ __launch_bounds__(256, 2)
void attn_kernel(const float* __restrict__ temp,
                 const float* __restrict__ polar,
                 float* __restrict__ out)
{
  __shared__ __align__(16) unsigned short sm_kv[9216];      // K:[128][72] / V:[64][136] bf16
  __shared__ __align__(16) unsigned short sm_q[64 * 72];    // Q tile [tok][d+8]
  __shared__ __align__(16) unsigned short sm_attn[4 * 16 * 40]; // per-wave [16][40]
  __shared__ float sm_phi[512];

  const int t    = threadIdx.x;
  const int lane = t & 63;
  const int wv   = t >> 6;      // wave 0..3
  const int l15  = lane & 15;
  const int q4   = lane >> 4;   // quad 0..3

  // XCD-aware swizzle: hw round-robins blockIdx%8 across XCDs; remap so
  // logical ids 0..511 (all rt+heads of windows 0..7) share XCD 0, etc.
  const int bid0 = blockIdx.x;
  const int bid  = ((bid0 & 7) << 9) | (bid0 >> 3);
  const int wi  = bid >> 6;         // window 0..63 (rt fastest -> K/V L2 reuse)
  const int hh  = (bid >> 3) & 7;   // head
  const int rt  = bid & 7;          // row-tile (64 rows)
  const int b   = wi >> 3;
  const int wx  = wi & 7;

  const size_t img = (size_t)512 * 4096;                 // elems per [B,C,H,W] tensor
  const size_t base_bh = (size_t)b * img + (size_t)(hh * 64) * 4096 + wx * 8;
  const float* qp = temp + base_bh;             // temp[0]
  const float* kp = temp + 8 * img + base_bh;   // temp[1]
  const float* vp = temp + 16 * img + base_bh;  // temp[2]

  // staging index decomposition (idx = it*256 + t):
  //   h = idx&1, dch = (idx>>1)&63, yl = idx>>7 = it*2 + (t>>7)
  const int s_h   = t & 1;
  const int s_dch = (t >> 1) & 63;
  const int s_y   = t >> 7;          // 0..1

  // ---- stage phi for the whole window (coord[...,1]) ----
  for (int i = t; i < 512; i += 256) {
    const int y = i >> 3, xl = i & 7;
    sm_phi[i] = polar[((size_t)b * 4096 + y * 64 + wx * 8 + xl) * 2 + 1];
  }

  // ---- prefetch K chunk 0 (latency hides under Q staging) ----
  float4 ld[8];
  #pragma unroll
  for (int it = 0; it < 8; ++it) {
    const int yl = it * 2 + s_y;
    ld[it] = *(const float4*)(kp + (size_t)s_dch * 4096 + yl * 64 + s_h * 4);
  }

  // ---- stage Q tile (64 tokens x 64 d): fp32 -> bf16, transpose to [tok][d] ----
  #pragma unroll
  for (int it = 0; it < 4; ++it) {
    const int y8 = it * 2 + s_y;       // 0..7
    const float4 v4 = *(const float4*)(qp + (size_t)s_dch * 4096 + (rt * 8 + y8) * 64 + s_h * 4);
    const int tok = y8 * 8 + s_h * 4;
    sm_q[(tok + 0) * 72 + s_dch] = f2bf(v4.x);
    sm_q[(tok + 1) * 72 + s_dch] = f2bf(v4.y);
    sm_q[(tok + 2) * 72 + s_dch] = f2bf(v4.z);
    sm_q[(tok + 3) * 72 + s_dch] = f2bf(v4.w);
  }

  // ---- write K chunk 0 ----
  unsigned short* smk = sm_kv;
  #pragma unroll
  for (int it = 0; it < 8; ++it) {
    const int yl  = it * 2 + s_y;
    const int tok = yl * 8 + s_h * 4;
    smk[(tok + 0) * 72 + s_dch] = f2bf(ld[it].x);
    smk[(tok + 1) * 72 + s_dch] = f2bf(ld[it].y);
    smk[(tok + 2) * 72 + s_dch] = f2bf(ld[it].z);
    smk[(tok + 3) * 72 + s_dch] = f2bf(ld[it].w);
  }
  __syncthreads();

  // Q A-fragments (resident): A[m=l15][k=q4*8+j], k-chunks of 32 over d=64
  bf16x8 qf[2];
  #pragma unroll
  for (int kc = 0; kc < 2; ++kc)
    qf[kc] = __builtin_bit_cast(
        bf16x8, *(const uint4*)&sm_q[(wv * 16 + l15) * 72 + kc * 32 + q4 * 8]);

  // ---- phase 1: score = Q K^T, K in 4 chunks of 128 tokens, prefetched ----
  f32x4 acc[32];
  #pragma unroll
  for (int jt = 0; jt < 32; ++jt) acc[jt] = (f32x4){0.f, 0.f, 0.f, 0.f};

  #pragma unroll
  for (int ch = 0; ch < 4; ++ch) {
    if (ch < 3) {                      // issue next chunk before MFMA phase
      #pragma unroll
      for (int it = 0; it < 8; ++it) {
        const int yl = it * 2 + s_y;
        ld[it] = *(const float4*)(kp + (size_t)s_dch * 4096 + ((ch + 1) * 16 + yl) * 64 + s_h * 4);
      }
    }
    #pragma unroll
    for (int j8 = 0; j8 < 8; ++j8) {
      const int jt = ch * 8 + j8;
      const bf16x8 kf0 = __builtin_bit_cast(
          bf16x8, *(const uint4*)&smk[(j8 * 16 + l15) * 72 + q4 * 8]);
      const bf16x8 kf1 = __builtin_bit_cast(
          bf16x8, *(const uint4*)&smk[(j8 * 16 + l15) * 72 + 32 + q4 * 8]);
      acc[jt] = __builtin_amdgcn_mfma_f32_16x16x32_bf16(qf[0], kf0, acc[jt], 0, 0, 0);
      acc[jt] = __builtin_amdgcn_mfma_f32_16x16x32_bf16(qf[1], kf1, acc[jt], 0, 0, 0);
    }
    __syncthreads();                   // all waves done reading chunk ch
    if (ch < 3) {
      #pragma unroll
      for (int it = 0; it < 8; ++it) {
        const int yl  = it * 2 + s_y;
        const int tok = yl * 8 + s_h * 4;
        smk[(tok + 0) * 72 + s_dch] = f2bf(ld[it].x);
        smk[(tok + 1) * 72 + s_dch] = f2bf(ld[it].y);
        smk[(tok + 2) * 72 + s_dch] = f2bf(ld[it].z);
        smk[(tok + 3) * 72 + s_dch] = f2bf(ld[it].w);
      }
      __syncthreads();
    }
  }

  // ---- prefetch V chunk 0 (latency hides under rpe/L1 VALU pass) ----
  #pragma unroll
  for (int it = 0; it < 8; ++it) {
    const int yl = it * 2 + s_y;
    ld[it] = *(const float4*)(vp + (size_t)s_dch * 4096 + yl * 64 + s_h * 4);
  }

  // ---- scale + rpe + row L1 ----
  // C layout: lane holds score[row=q4*4+r][col=jt*16+l15]
  float phi_r[4];
  #pragma unroll
  for (int r = 0; r < 4; ++r)
    phi_r[r] = sm_phi[rt * 64 + wv * 16 + q4 * 4 + r];
  float l1p[4] = {0.f, 0.f, 0.f, 0.f};
  #pragma unroll
  for (int jt = 0; jt < 32; ++jt) {
    const float phi_c = sm_phi[jt * 16 + l15];
    #pragma unroll
    for (int r = 0; r < 4; ++r) {
      const float s = acc[jt][r] * 0.125f + (phi_r[r] - phi_c);
      acc[jt][r] = s;
      l1p[r] += fabsf(s);
    }
  }
  #pragma unroll
  for (int r = 0; r < 4; ++r) {
    float v = l1p[r];
    v += __shfl_xor(v, 1, 16);
    v += __shfl_xor(v, 2, 16);
    v += __shfl_xor(v, 4, 16);
    v += __shfl_xor(v, 8, 16);
    l1p[r] = 1.5707963267948966f / (v + 1e-8f);   // fold pi/2 into reciprocal
  }

  // ---- write V chunk 0 (V wants [d][tok], stride 136) ----
  unsigned short* smv = sm_kv;
  #pragma unroll
  for (int it = 0; it < 8; ++it) {
    const int yl = it * 2 + s_y;
    uint2 p;
    p.x = cvtpk(ld[it].x, ld[it].y);
    p.y = cvtpk(ld[it].z, ld[it].w);
    *(uint2*)&smv[s_dch * 136 + yl * 8 + s_h * 4] = p;
  }
  __syncthreads();

  // ---- phase 2: out = attn @ V (attn = 2*sin^2(x/2) = 1-cos(x)) ----
  f32x4 oacc[4];
  #pragma unroll
  for (int nt = 0; nt < 4; ++nt) oacc[nt] = (f32x4){0.f, 0.f, 0.f, 0.f};

  unsigned short* sma = sm_attn + wv * (16 * 40);
  #pragma unroll
  for (int vc = 0; vc < 4; ++vc) {
    if (vc < 3) {                      // issue next chunk before compute
      #pragma unroll
      for (int it = 0; it < 8; ++it) {
        const int yl = it * 2 + s_y;
        ld[it] = *(const float4*)(vp + (size_t)s_dch * 4096 + ((vc + 1) * 16 + yl) * 64 + s_h * 4);
      }
    }
    #pragma unroll
    for (int k2 = 0; k2 < 4; ++k2) {            // 32 j-columns per iteration
      const int jt0 = vc * 8 + k2 * 2;
      #pragma unroll
      for (int jl = 0; jl < 2; ++jl) {
        const int jt = jt0 + jl;
        #pragma unroll
        for (int r = 0; r < 4; ++r) {
          const float x  = acc[jt][r] * l1p[r];
          const float sn = __sinf(0.5f * x);
          sma[(q4 * 4 + r) * 40 + jl * 16 + l15] = f2bf(2.f * sn * sn);
        }
      }
      // C-layout -> A-operand layout via per-wave LDS round-trip
      const bf16x8 af = __builtin_bit_cast(
          bf16x8, *(const uint4*)&sma[l15 * 40 + q4 * 8]);
      #pragma unroll
      for (int nt = 0; nt < 4; ++nt) {
        const bf16x8 vf = __builtin_bit_cast(
            bf16x8, *(const uint4*)&smv[(nt * 16 + l15) * 136 + k2 * 32 + q4 * 8]);
        oacc[nt] = __builtin_amdgcn_mfma_f32_16x16x32_bf16(af, vf, oacc[nt], 0, 0, 0);
      }
    }
    __syncthreads();                   // all waves done reading chunk vc
    if (vc < 3) {
      #pragma unroll
      for (int it = 0; it < 8; ++it) {
        const int yl = it * 2 + s_y;
        uint2 p;
        p.x = cvtpk(ld[it].x, ld[it].y);
        p.y = cvtpk(ld[it].z, ld[it].w);
        *(uint2*)&smv[s_dch * 136 + yl * 8 + s_h * 4] = p;
      }
      __syncthreads();
    }
  }

  // ---- epilogue: add onto lepe already in d_out (fp32 RMW) ----
  #pragma unroll
  for (int r = 0; r < 4; ++r) {
    const int srow = rt * 64 + wv * 16 + q4 * 4 + r;   // token in window
    const int y = srow >> 3, xl = srow & 7;
    const size_t obase = ((size_t)b * 4096 + y * 64 + wx * 8 + xl) * 512 + hh * 64;
    #pragma unroll
    for (int nt = 0; nt < 4; ++nt) {
      const size_t oi = obase + nt * 16 + l15;
      out[oi] += oacc[nt][r];
    }
  }
}

extern "C" void kernel_launch(void* const* d_in, const int* in_sizes, int n_in,
                              void* d_out, int out_size, void* d_ws, size_t ws_size,
                              hipStream_t stream) {
  const float* temp  = (const float*)d_in[0]; // [3,8,512,64,64] fp32
  const float* polar = (const float*)d_in[1]; // [8,64,64,2] fp32
  const float* cw    = (const float*)d_in[2]; // [512,1,3,3] fp32
  const float* cb    = (const float*)d_in[3]; // [512] fp32
  float* out = (float*)d_out;                 // [8,4096,512] fp32

  lepe_kernel<<<1024, 256, 0, stream>>>(temp, cw, cb, out);
  attn_kernel<<<4096, 256, 0, stream>>>(temp, polar, out);
}